// Round 7
// baseline (573.733 us; speedup 1.0000x reference)
//
#include <hip/hip_runtime.h>
#include <hip/hip_fp16.h>

#define NU 100000
#define NI 50000
#define NN 150000          // NU + NI (even)
#define HH 64
#define NE 1200000

#define SCAN_CHUNK 1024
#define NBLK ((NN + SCAN_CHUNK - 1) / SCAN_CHUNK)   // 147
#define SCAN_GRID (NBLK + 1)                         // +1 W-combine block = 148

#define RANK_BLOCKS  ((NE / 8 + 255) / 256)          // 587
#define RC_GRID 10000                                // rank interleaved 1-in-16 among concat
#define AGG_GRID 2048                                // persistent blocks, grid-stride pairs
#define NPAIRS (NN / 2)                              // 75000

// ---------------------------------------------------------------- rank + concat (fused, interleaved)
// Every 16th block is a rank block (587 of 625 slots used); the rest are concat
// blocks (exactly 9375). Interleaving spreads the latency-bound atomic waves
// across ALL CUs so they co-reside with streaming concat waves — the atomic
// round-trips hide under streaming issue slots (round-4's partition put them on
// disjoint CUs and the two phases serialized).
__global__ __launch_bounds__(256) void k_rank_concat(
    const int4* __restrict__ dst4, int* __restrict__ counts, int4* __restrict__ rank4,
    const float4* __restrict__ users, const float4* __restrict__ items,
    __half2* __restrict__ xs, float4* __restrict__ out,
    __half* __restrict__ pad0, __half* __restrict__ pad1,
    float* __restrict__ dinv, float* __restrict__ p1u) {
    int bid = blockIdx.x;
    if ((bid & 15) == 0) {
        int rb = bid >> 4;                           // rank block 0..624
        if (rb >= RANK_BLOCKS) return;
        if (rb == 0 && threadIdx.x < 18) {
            if (threadIdx.x < 8)       ((int4*)pad0)[threadIdx.x] = make_int4(0, 0, 0, 0);
            else if (threadIdx.x < 16) ((int4*)pad1)[threadIdx.x - 8] = make_int4(0, 0, 0, 0);
            else if (threadIdx.x == 16) dinv[NN] = 0.f;
            else                        p1u[NN] = 0.f;
        }
        int t = rb * 256 + threadIdx.x;              // over NE/8
        if (t >= NE / 8) return;
        int4 d0 = dst4[2 * t], d1 = dst4[2 * t + 1];
        int4 r0, r1;
        r0.x = atomicAdd(&counts[d0.x], 1);
        r0.y = atomicAdd(&counts[d0.y], 1);
        r0.z = atomicAdd(&counts[d0.z], 1);
        r0.w = atomicAdd(&counts[d0.w], 1);
        r1.x = atomicAdd(&counts[d1.x], 1);
        r1.y = atomicAdd(&counts[d1.y], 1);
        r1.z = atomicAdd(&counts[d1.z], 1);
        r1.w = atomicAdd(&counts[d1.w], 1);
        rank4[2 * t]     = r0;
        rank4[2 * t + 1] = r1;
    } else {
        // concat block index = bid minus rank slots before it
        int cb = bid - (bid >> 4) - 1;               // 0..9374
        int i = cb * 256 + threadIdx.x;              // over NN*16 float4
        const int UB = NU * 16;
        float4 v;
        if (i < UB) {
            v = users[i];
            out[UB + i] = v;                         // O1 = users_emb passthrough
        } else {
            int j = i - UB;
            v = items[j];
            out[2 * UB + NI * 16 + j] = v;           // O3 = items_emb passthrough
        }
        xs[2 * i]     = __halves2half2(__float2half_rn(v.x), __float2half_rn(v.y));
        xs[2 * i + 1] = __halves2half2(__float2half_rn(v.z), __float2half_rn(v.w));
    }
}

// ---------------------------------------------------------------- scan + fill (fused)
// 147 lookback-scan blocks + 1 W-combine block = 148 blocks, all co-resident.
// After row_ptr publishes: device barrier (threadfence + arrival counter) ->
// same blocks grid-stride the CSR fill. Saves one dispatch.
__global__ __launch_bounds__(256) void k_scan_fill(
    const int* __restrict__ counts,
    float* __restrict__ dinv, float* __restrict__ dinv2,
    int* __restrict__ row_ptr, unsigned int* __restrict__ state,
    const float* __restrict__ Wfull, const float* __restrict__ bfull,
    float* __restrict__ What, float* __restrict__ cvec,
    const int4* __restrict__ src4, const int4* __restrict__ dst4,
    const int4* __restrict__ rank4, int* __restrict__ col) {
    __shared__ float smem[HH * HH];   // W12 for combine block; 256 ints for scan
    __shared__ int s_prefix;
    int t = threadIdx.x;
    int b = blockIdx.x;

    if (b == NBLK) {
        // ---- W-combine (one block) ----
        int r = t >> 2, j0 = (t & 3) * 16;
        const float* W0 = Wfull;
        const float* W1 = Wfull + HH * HH;
        const float* W2 = Wfull + 2 * HH * HH;
        float acc[16];
#pragma unroll
        for (int j = 0; j < 16; ++j) acc[j] = 0.f;
        for (int k = 0; k < HH; ++k) {
            float a = W1[r * HH + k];
            const float* bp = W2 + k * HH + j0;
#pragma unroll
            for (int j = 0; j < 16; ++j) acc[j] += a * bp[j];
        }
#pragma unroll
        for (int j = 0; j < 16; ++j) smem[r * HH + j0 + j] = acc[j];   // W12 = W1*W2
        if (t < HH) {                       // c1 = b1^T W2
            float s = 0.f;
            for (int k = 0; k < HH; ++k) s += bfull[HH + k] * W2[k * HH + t];
            cvec[HH + t] = s;
        }
        __syncthreads();
#pragma unroll
        for (int j = 0; j < 16; ++j) acc[j] = 0.f;
        for (int k = 0; k < HH; ++k) {      // What = W0 * W12
            float a = W0[r * HH + k];
            const float* bp = smem + k * HH + j0;
#pragma unroll
            for (int j = 0; j < 16; ++j) acc[j] += a * bp[j];
        }
#pragma unroll
        for (int j = 0; j < 16; ++j) What[r * HH + j0 + j] = acc[j];
        if (t < HH) {                       // c0 = b0^T W12
            float s = 0.f;
            for (int k = 0; k < HH; ++k) s += bfull[k] * smem[k * HH + t];
            cvec[t] = s;
        }
    } else {
        int* sd = (int*)smem;
        int base = b * SCAN_CHUNK + t * 4;
        int c[4];
        if (base + 3 < NN) {
            int4 v = *(const int4*)(counts + base);
            c[0] = v.x; c[1] = v.y; c[2] = v.z; c[3] = v.w;
        } else {
#pragma unroll
            for (int i = 0; i < 4; ++i) c[i] = (base + i < NN) ? counts[base + i] : 0;
        }
#pragma unroll
        for (int i = 0; i < 4; ++i)
            if (base + i < NN) {
                dinv[base + i]  = rsqrtf((float)(c[i] + 1));
                dinv2[base + i] = 1.0f / (float)(c[i] + 1);
            }

        int tt = c[0] + c[1] + c[2] + c[3];
        sd[t] = tt; __syncthreads();
        for (int off = 1; off < 256; off <<= 1) {      // inclusive Hillis-Steele
            int x = (t >= off) ? sd[t - off] : 0;
            __syncthreads();
            sd[t] += x;
            __syncthreads();
        }

        if (t == 0) {
            unsigned int agg = (unsigned int)sd[255];
            if (b == 0) {
                __hip_atomic_store(&state[0], (2u << 30) | agg, __ATOMIC_RELEASE,
                                   __HIP_MEMORY_SCOPE_AGENT);
                s_prefix = 0;
            } else {
                __hip_atomic_store(&state[b], (1u << 30) | agg, __ATOMIC_RELEASE,
                                   __HIP_MEMORY_SCOPE_AGENT);
                unsigned int prefix = 0;
                int p = b - 1;
                while (true) {
                    unsigned int s = __hip_atomic_load(&state[p], __ATOMIC_ACQUIRE,
                                                       __HIP_MEMORY_SCOPE_AGENT);
                    unsigned int fl = s >> 30;
                    if (fl == 0u) { __builtin_amdgcn_s_sleep(1); continue; }
                    prefix += s & 0x3FFFFFFFu;
                    if (fl == 2u) break;
                    --p;
                }
                __hip_atomic_store(&state[b], (2u << 30) | (prefix + agg),
                                   __ATOMIC_RELEASE, __HIP_MEMORY_SCOPE_AGENT);
                s_prefix = (int)prefix;
            }
        }
        __syncthreads();

        int off0 = s_prefix + (sd[t] - tt);             // exclusive offset
        int run = 0;
#pragma unroll
        for (int i = 0; i < 4; ++i) {
            if (base + i < NN) row_ptr[base + i] = off0 + run;
            run += c[i];
        }
        if (b == NBLK - 1 && t == 0) row_ptr[NN] = NE;
    }

    // ---- device barrier: all 148 blocks arrive, then fill ----
    unsigned int* done = state + 192;   // zeroed by the memset
    __threadfence();
    __syncthreads();
    if (t == 0) {
        __hip_atomic_fetch_add(done, 1u, __ATOMIC_ACQ_REL, __HIP_MEMORY_SCOPE_AGENT);
        while (__hip_atomic_load(done, __ATOMIC_ACQUIRE, __HIP_MEMORY_SCOPE_AGENT)
               < (unsigned int)SCAN_GRID)
            __builtin_amdgcn_s_sleep(4);
    }
    __syncthreads();
    __threadfence();

    // CSR fill: col[row_ptr[dst] + rank] = src. 8 edges/item, grid-stride.
    for (int e = b * 256 + t; e < NE / 8; e += SCAN_GRID * 256) {
        int4 s0 = src4[2 * e],  s1 = src4[2 * e + 1];
        int4 d0 = dst4[2 * e],  d1 = dst4[2 * e + 1];
        int4 r0 = rank4[2 * e], r1 = rank4[2 * e + 1];
        int p0 = row_ptr[d0.x], p1 = row_ptr[d0.y], p2 = row_ptr[d0.z], p3 = row_ptr[d0.w];
        int p4 = row_ptr[d1.x], p5 = row_ptr[d1.y], p6 = row_ptr[d1.z], p7 = row_ptr[d1.w];
        col[p0 + r0.x] = s0.x;
        col[p1 + r0.y] = s0.y;
        col[p2 + r0.z] = s0.z;
        col[p3 + r0.w] = s0.w;
        col[p4 + r1.x] = s1.x;
        col[p5 + r1.y] = s1.y;
        col[p6 + r1.z] = s1.z;
        col[p7 + r1.w] = s1.w;
    }
}

// ---------------------------------------------------------------- aggregation (octet-gather, persistent)
// PERSISTENT grid: 2048 blocks (0 LDS, 256 thr) stay fully resident (~8
// blocks/CU -> ~32 waves/CU vs 44% occupancy with 18750 short blocks); each
// wave grid-strides over node PAIRS. More resident waves = more outstanding
// gathers = higher throughput on this latency-bound loop.
// Wave = 8 octets x 8 lanes, 2 nodes/pair; lane holds 8 half-features (16 B).
// UMODE==1 (xs UNSCALED): gather applies dinv[r] via FMA (shared with the
//   u-sum broadcast load); writes u1 and p1u = dinv*u1.
// UMODE==2: input prescaled; u-sum over pin=p1u; writes u2.
// u over-counts 8x (one add per octet lane); fixed by *0.125.
template <int UMODE>
__global__ __launch_bounds__(256) void k_aggregate(
    const __half* __restrict__ x, __half* __restrict__ y,
    const float* __restrict__ scale,
    const int* __restrict__ row_ptr, const int* __restrict__ col,
    const float* __restrict__ dinv, const float* __restrict__ pin,
    float* __restrict__ uout, float* __restrict__ pout) {
    int lane = threadIdx.x & 63;
    int waveId = blockIdx.x * 4 + (threadIdx.x >> 6);
    const int NW = AGG_GRID * 4;         // total waves
    int o  = lane >> 3;                  // octet 0..7 (row slot within a step)
    int f8 = (lane & 7) << 3;            // 8-feature base for this lane

    for (int pair = waveId; pair < NPAIRS; pair += NW) {
        int na = pair * 2;
        int nb = na + 1;                 // NN even: always valid

        float a[8], b[8];
#pragma unroll
        for (int j = 0; j < 8; ++j) { a[j] = 0.f; b[j] = 0.f; }
        float ua = 0.f, ub = 0.f;

#define GATHER(r, acc, uacc)                                               \
        {                                                                  \
            int4 raw = *(const int4*)(x + (size_t)(r) * HH + f8);          \
            float dr = 1.f;                                                \
            if (UMODE) { dr = pin[r]; uacc += dr; }                        \
            __half2* hp = (__half2*)&raw;                                  \
            _Pragma("unroll")                                              \
            for (int j = 0; j < 4; ++j) {                                  \
                float2 f = __half22float2(hp[j]);                          \
                if (UMODE == 1) { acc[2 * j] += dr * f.x; acc[2 * j + 1] += dr * f.y; } \
                else            { acc[2 * j] += f.x;      acc[2 * j + 1] += f.y; }      \
            }                                                              \
        }

        int ea = row_ptr[na], enda = row_ptr[na + 1];
        int eb = enda,        endb = row_ptr[nb + 1];   // rows adjacent

        // prologue: octet 0 = self row, octets 1-7 = first 7 edges (pad -> NN)
        {
            int ia = ea + o - 1;
            int ib = eb + o - 1;
            int rA = (o == 0) ? na : ((ia < enda) ? col[ia] : NN);
            int rB = (o == 0) ? nb : ((ib < endb) ? col[ib] : NN);
            GATHER(rA, a, ua);
            GATHER(rB, b, ub);
            ea += 7; eb += 7;
        }
        // main loop, unrolled x2: 16 edges per node per iteration
        while (ea < enda || eb < endb) {
            int iA0 = ea + o,     iA1 = ea + 8 + o;
            int iB0 = eb + o,     iB1 = eb + 8 + o;
            int rA0 = (iA0 < enda) ? col[iA0] : NN;
            int rA1 = (iA1 < enda) ? col[iA1] : NN;
            int rB0 = (iB0 < endb) ? col[iB0] : NN;
            int rB1 = (iB1 < endb) ? col[iB1] : NN;
            GATHER(rA0, a, ua);
            GATHER(rA1, a, ua);
            GATHER(rB0, b, ub);
            GATHER(rB1, b, ub);
            ea += 16; eb += 16;
        }
#undef GATHER

        // cross-octet reduction: octets differ in lane bits 3,4,5
#pragma unroll
        for (int j = 0; j < 8; ++j) {
            a[j] += __shfl_xor(a[j], 8);  b[j] += __shfl_xor(b[j], 8);
            a[j] += __shfl_xor(a[j], 16); b[j] += __shfl_xor(b[j], 16);
            a[j] += __shfl_xor(a[j], 32); b[j] += __shfl_xor(b[j], 32);
        }
        if (UMODE) {
            ua += __shfl_xor(ua, 8);  ub += __shfl_xor(ub, 8);
            ua += __shfl_xor(ua, 16); ub += __shfl_xor(ub, 16);
            ua += __shfl_xor(ua, 32); ub += __shfl_xor(ub, 32);
        }

        // octets 0/1 store node a / node b rows (8 lanes x 16 B = one 128-B row)
        if (o < 2) {
            int   n  = (o == 0) ? na : nb;
            float dv = scale[n];
            __half2 h[4];
#pragma unroll
            for (int j = 0; j < 4; ++j) {
                float x0 = (o == 0) ? a[2 * j]     : b[2 * j];
                float x1 = (o == 0) ? a[2 * j + 1] : b[2 * j + 1];
                h[j] = __halves2half2(__float2half_rn(dv * x0), __float2half_rn(dv * x1));
            }
            *(int4*)(y + (size_t)n * HH + f8) = *(int4*)h;
        }
        if (UMODE && lane < 2) {
            int n = na + lane;
            float s = ((lane == 0) ? ua : ub) * 0.125f;   // each octet counted 8x
            float dvn = dinv[n];
            float u = dvn * s;
            uout[n] = u;
            if (UMODE == 1) pout[n] = dvn * u;            // prescaled for next u-pass
        }
    }
}

// ---------------------------------------------------------------- final GEMM
// out = (A^3 x0) @ What + u2 c0^T + u1 c1^T + 1 b2^T, split fp32 write.
#define GR 128
#define XSS 65   // +1 pad: conflict-free scalar broadcasts
__global__ __launch_bounds__(256) void k_gemm_final(
    const __half* __restrict__ y, const float* __restrict__ W,
    const float* __restrict__ b2, const float* __restrict__ cvec,
    const float* __restrict__ u1, const float* __restrict__ u2,
    float* __restrict__ out_lo, float* __restrict__ out_hi) {
    __shared__ float xs[GR * XSS];   // 33.3 KB
    __shared__ float ws[HH * HH];    // 16 KB
    int t = threadIdx.x;
    int rowBase = blockIdx.x * GR;

    {   // stage W: 1024 float4 / 256 threads
        const float4* W4 = (const float4*)W;
        float4* ws4 = (float4*)ws;
#pragma unroll
        for (int i = 0; i < 4; ++i) ws4[i * 256 + t] = W4[i * 256 + t];
    }
#pragma unroll
    for (int it = 0; it < 4; ++it) {
        int g = it * 256 + t;        // 0..1023
        int r = g >> 3;
        int c0 = (g & 7) * 8;
        int row = rowBase + r;
        if (row < NN) {
            int4 raw = *(const int4*)(y + (size_t)row * HH + c0);   // 8 halves
            __half2 h0 = *(__half2*)&raw.x, h1 = *(__half2*)&raw.y;
            __half2 h2 = *(__half2*)&raw.z, h3 = *(__half2*)&raw.w;
            float2 f0 = __half22float2(h0), f1 = __half22float2(h1);
            float2 f2 = __half22float2(h2), f3 = __half22float2(h3);
            float* dp = xs + r * XSS + c0;
            dp[0] = f0.x; dp[1] = f0.y; dp[2] = f1.x; dp[3] = f1.y;
            dp[4] = f2.x; dp[5] = f2.y; dp[6] = f3.x; dp[7] = f3.y;
        }
    }
    __syncthreads();

    int tx = t & 7;        // 8 col-groups of 8
    int ty = t >> 3;       // 32 row-groups of 4
    int j0 = tx * 8;
    int r0 = ty * 4;

    float acc[4][8];
#pragma unroll
    for (int i = 0; i < 4; ++i)
#pragma unroll
        for (int j = 0; j < 8; ++j) acc[i][j] = 0.f;

    for (int k = 0; k < HH; ++k) {
        float4 w0 = *(const float4*)(ws + k * HH + j0);
        float4 w1 = *(const float4*)(ws + k * HH + j0 + 4);
        float wv[8] = {w0.x, w0.y, w0.z, w0.w, w1.x, w1.y, w1.z, w1.w};
#pragma unroll
        for (int i = 0; i < 4; ++i) {
            float xv = xs[(r0 + i) * XSS + k];
#pragma unroll
            for (int j = 0; j < 8; ++j) acc[i][j] += xv * wv[j];
        }
    }

    float c0j[8], c1j[8], b2j[8];
#pragma unroll
    for (int j = 0; j < 8; ++j) {
        c0j[j] = cvec[j0 + j];
        c1j[j] = cvec[HH + j0 + j];
        b2j[j] = b2[j0 + j];
    }

#pragma unroll
    for (int i = 0; i < 4; ++i) {
        int r = rowBase + r0 + i;
        if (r >= NN) continue;
        float u2r = u2[r], u1r = u1[r];
        float base[8];
#pragma unroll
        for (int j = 0; j < 8; ++j) base[j] = u2r * c0j[j] + u1r * c1j[j] + b2j[j];
        float4 o0 = make_float4(acc[i][0] + base[0], acc[i][1] + base[1],
                                acc[i][2] + base[2], acc[i][3] + base[3]);
        float4 o1 = make_float4(acc[i][4] + base[4], acc[i][5] + base[5],
                                acc[i][6] + base[6], acc[i][7] + base[7]);
        float* d = (r < NU) ? (out_lo + (size_t)r * HH)
                            : (out_hi + (size_t)(r - NU) * HH);
        *(float4*)(d + j0) = o0;
        *(float4*)(d + j0 + 4) = o1;
    }
}

// ---------------------------------------------------------------- launch
extern "C" void kernel_launch(void* const* d_in, const int* in_sizes, int n_in,
                              void* d_out, int out_size, void* d_ws, size_t ws_size,
                              hipStream_t stream) {
    const int*   edge  = (const int*)d_in[0];
    const int*   src   = edge;           // edge_index[0]
    const int*   dst   = edge + NE;      // edge_index[1]
    const float* users = (const float*)d_in[1];
    const float* items = (const float*)d_in[2];
    const float* Ws    = (const float*)d_in[3];   // [3][64][64]
    const float* bs    = (const float*)d_in[4];   // [3][64]
    float*       out   = (float*)d_out;

    // workspace carve (~52 MB). Xs row NN, dinv[NN], p1u[NN] are zeroed pads
    // (rank block 0). state (lookback + barrier counter at +192) sits directly
    // before counts: one memset covers both.
    char* w = (char*)d_ws;
    __half* Xs0     = (__half*)w; w += (size_t)(NN + 1) * HH * 2;   // 19.2 MB
    __half* Xs1     = (__half*)w; w += (size_t)(NN + 1) * HH * 2;   // 19.2 MB
    float*  dinv    = (float*)w;  w += (size_t)(NN + 1) * 4;
    float*  dinv2   = (float*)w;  w += (size_t)NN * 4;
    float*  u1      = (float*)w;  w += (size_t)NN * 4;
    float*  p1u     = (float*)w;  w += (size_t)(NN + 1) * 4;
    float*  u2      = (float*)w;  w += (size_t)NN * 4;
    float*  What    = (float*)w;  w += (size_t)HH * HH * 4;         // 16 KB
    float*  cvec    = (float*)w;  w += (size_t)2 * HH * 4;          // c0, c1
    unsigned int* state = (unsigned int*)w; w += 256 * 4;
    int*    counts  = (int*)w;    w += (size_t)NN * 4;
    int*    row_ptr = (int*)w;    w += (size_t)(NN + 1) * 4;
    w += 12;                                                  // realign to 16
    int*    col     = (int*)w;    w += (size_t)NE * 4;        // 4.8 MB
    int*    rank    = (int*)w;    w += (size_t)NE * 4;        // 4.8 MB
    (void)ws_size; (void)in_sizes; (void)n_in; (void)out_size;

    hipMemsetAsync(state, 0, (size_t)(256 + NN) * sizeof(int), stream);

    k_rank_concat<<<RC_GRID, 256, 0, stream>>>(
        (const int4*)dst, counts, (int4*)rank,
        (const float4*)users, (const float4*)items, (__half2*)Xs0, (float4*)out,
        Xs0 + (size_t)NN * HH, Xs1 + (size_t)NN * HH, dinv, p1u);
    k_scan_fill<<<SCAN_GRID, 256, 0, stream>>>(
        counts, dinv, dinv2, row_ptr, state, Ws, bs, What, cvec,
        (const int4*)src, (const int4*)dst, (const int4*)rank, col);

    // A^3 chain (persistent grids) + single final gemm
    k_aggregate<1><<<AGG_GRID, 256, 0, stream>>>(
        Xs0, Xs1, dinv2, row_ptr, col, dinv, dinv, u1, p1u);
    k_aggregate<2><<<AGG_GRID, 256, 0, stream>>>(
        Xs1, Xs0, dinv2, row_ptr, col, dinv, p1u, u2, nullptr);
    k_aggregate<0><<<AGG_GRID, 256, 0, stream>>>(
        Xs0, Xs1, dinv, row_ptr, col, nullptr, nullptr, nullptr, nullptr);

    const int GEMM_BLOCKS = (NN + GR - 1) / GR;
    k_gemm_final<<<GEMM_BLOCKS, 256, 0, stream>>>(
        Xs1, What, bs + 2 * HH, cvec, u1, u2,
        out /* x_users */, out + (size_t)2 * NU * HH /* x_items */);
}

// Round 8
// 388.104 us; speedup vs baseline: 1.4783x; 1.4783x over previous
//
#include <hip/hip_runtime.h>
#include <hip/hip_fp16.h>

#define NU 100000
#define NI 50000
#define NN 150000          // NU + NI (even)
#define HH 64
#define NE 1200000

#define SCAN_CHUNK 1024
#define NBLK ((NN + SCAN_CHUNK - 1) / SCAN_CHUNK)   // 147
#define AGG_BLOCKS (NN / 8)                          // 18750 (8 nodes/block)

#define RANK_BLOCKS   ((NE / 16 + 255) / 256)        // 293 (16 edges/thread)
#define CONCAT4_BLOCKS (NN * 16 / 256)               // 9375 (exact; thread = 1 float4)
#define FILL_BLOCKS   ((NE / 8 + 255) / 256)         // 586

// ---------------------------------------------------------------- rank + concat (fused, partitioned)
// Rank blocks FIRST (they start early, finish while concat streams), concat
// blocks after. 16 edges/thread: 16 independent atomicAdd-returns in flight
// per thread (latency/throughput-bound op — depth is the only lever).
// Rank block 0 also zeroes the gather pads: Xs rows NN, dinv[NN], p1u[NN].
__global__ __launch_bounds__(256) void k_rank_concat(
    const int4* __restrict__ dst4, int* __restrict__ counts, int4* __restrict__ rank4,
    const float4* __restrict__ users, const float4* __restrict__ items,
    __half2* __restrict__ xs, float4* __restrict__ out,
    __half* __restrict__ pad0, __half* __restrict__ pad1,
    float* __restrict__ dinv, float* __restrict__ p1u) {
    if (blockIdx.x < RANK_BLOCKS) {
        if (blockIdx.x == 0 && threadIdx.x < 18) {
            if (threadIdx.x < 8)       ((int4*)pad0)[threadIdx.x] = make_int4(0, 0, 0, 0);
            else if (threadIdx.x < 16) ((int4*)pad1)[threadIdx.x - 8] = make_int4(0, 0, 0, 0);
            else if (threadIdx.x == 16) dinv[NN] = 0.f;
            else                        p1u[NN] = 0.f;
        }
        int t = blockIdx.x * 256 + threadIdx.x;      // over NE/16
        if (t >= NE / 16) return;
        int4 d0 = dst4[4 * t],     d1 = dst4[4 * t + 1];
        int4 d2 = dst4[4 * t + 2], d3 = dst4[4 * t + 3];
        int4 r0, r1, r2, r3;
        r0.x = atomicAdd(&counts[d0.x], 1);
        r0.y = atomicAdd(&counts[d0.y], 1);
        r0.z = atomicAdd(&counts[d0.z], 1);
        r0.w = atomicAdd(&counts[d0.w], 1);
        r1.x = atomicAdd(&counts[d1.x], 1);
        r1.y = atomicAdd(&counts[d1.y], 1);
        r1.z = atomicAdd(&counts[d1.z], 1);
        r1.w = atomicAdd(&counts[d1.w], 1);
        r2.x = atomicAdd(&counts[d2.x], 1);
        r2.y = atomicAdd(&counts[d2.y], 1);
        r2.z = atomicAdd(&counts[d2.z], 1);
        r2.w = atomicAdd(&counts[d2.w], 1);
        r3.x = atomicAdd(&counts[d3.x], 1);
        r3.y = atomicAdd(&counts[d3.y], 1);
        r3.z = atomicAdd(&counts[d3.z], 1);
        r3.w = atomicAdd(&counts[d3.w], 1);
        rank4[4 * t]     = r0;
        rank4[4 * t + 1] = r1;
        rank4[4 * t + 2] = r2;
        rank4[4 * t + 3] = r3;
    } else {
        // concat: thread = one float4 (dense lane addressing).
        int i = (blockIdx.x - RANK_BLOCKS) * 256 + threadIdx.x;   // over NN*16
        const int UB = NU * 16;
        float4 v;
        if (i < UB) {
            v = users[i];
            out[UB + i] = v;                         // O1 = users_emb passthrough
        } else {
            int j = i - UB;
            v = items[j];
            out[2 * UB + NI * 16 + j] = v;           // O3 = items_emb passthrough
        }
        xs[2 * i]     = __halves2half2(__float2half_rn(v.x), __float2half_rn(v.y));
        xs[2 * i + 1] = __halves2half2(__float2half_rn(v.z), __float2half_rn(v.w));
    }
}

// ---------------------------------------------------------------- single-pass scan (decoupled lookback)
// 147 scan blocks + 1 W-combine block (148 < 256 CUs: co-resident, spin safe).
// state[b]: 0 = invalid, (1<<30)|aggregate, (2<<30)|inclusive_prefix.
// Emits dinv[n] = rsqrt(deg+1), dinv2[n] = 1/(deg+1).
// Block NBLK instead computes What = W0 W1 W2, c0 = b0^T W1 W2, c1 = b1^T W2.
__global__ __launch_bounds__(256) void k_scan(const int* __restrict__ counts,
                                              float* __restrict__ dinv,
                                              float* __restrict__ dinv2,
                                              int* __restrict__ row_ptr,
                                              unsigned int* __restrict__ state,
                                              const float* __restrict__ Wfull,
                                              const float* __restrict__ bfull,
                                              float* __restrict__ What,
                                              float* __restrict__ cvec) {
    __shared__ float smem[HH * HH];   // W12 for the combine block; 256 ints for scan
    __shared__ int s_prefix;
    int t = threadIdx.x;
    int b = blockIdx.x;

    if (b == NBLK) {
        // ---- W-combine (one block) ----
        int r = t >> 2, j0 = (t & 3) * 16;
        const float* W0 = Wfull;
        const float* W1 = Wfull + HH * HH;
        const float* W2 = Wfull + 2 * HH * HH;
        float acc[16];
#pragma unroll
        for (int j = 0; j < 16; ++j) acc[j] = 0.f;
        for (int k = 0; k < HH; ++k) {
            float a = W1[r * HH + k];
            const float* bp = W2 + k * HH + j0;
#pragma unroll
            for (int j = 0; j < 16; ++j) acc[j] += a * bp[j];
        }
#pragma unroll
        for (int j = 0; j < 16; ++j) smem[r * HH + j0 + j] = acc[j];   // W12 = W1*W2
        if (t < HH) {                       // c1 = b1^T W2
            float s = 0.f;
            for (int k = 0; k < HH; ++k) s += bfull[HH + k] * W2[k * HH + t];
            cvec[HH + t] = s;
        }
        __syncthreads();
#pragma unroll
        for (int j = 0; j < 16; ++j) acc[j] = 0.f;
        for (int k = 0; k < HH; ++k) {      // What = W0 * W12
            float a = W0[r * HH + k];
            const float* bp = smem + k * HH + j0;
#pragma unroll
            for (int j = 0; j < 16; ++j) acc[j] += a * bp[j];
        }
#pragma unroll
        for (int j = 0; j < 16; ++j) What[r * HH + j0 + j] = acc[j];
        if (t < HH) {                       // c0 = b0^T W12
            float s = 0.f;
            for (int k = 0; k < HH; ++k) s += bfull[k] * smem[k * HH + t];
            cvec[t] = s;
        }
        return;
    }

    int* sd = (int*)smem;
    int base = b * SCAN_CHUNK + t * 4;
    int c[4];
    if (base + 3 < NN) {
        int4 v = *(const int4*)(counts + base);
        c[0] = v.x; c[1] = v.y; c[2] = v.z; c[3] = v.w;
    } else {
#pragma unroll
        for (int i = 0; i < 4; ++i) c[i] = (base + i < NN) ? counts[base + i] : 0;
    }
#pragma unroll
    for (int i = 0; i < 4; ++i)
        if (base + i < NN) {
            dinv[base + i]  = rsqrtf((float)(c[i] + 1));
            dinv2[base + i] = 1.0f / (float)(c[i] + 1);
        }

    int tt = c[0] + c[1] + c[2] + c[3];
    sd[t] = tt; __syncthreads();
    for (int off = 1; off < 256; off <<= 1) {          // inclusive Hillis-Steele
        int x = (t >= off) ? sd[t - off] : 0;
        __syncthreads();
        sd[t] += x;
        __syncthreads();
    }

    if (t == 0) {
        unsigned int agg = (unsigned int)sd[255];
        if (b == 0) {
            __hip_atomic_store(&state[0], (2u << 30) | agg, __ATOMIC_RELEASE,
                               __HIP_MEMORY_SCOPE_AGENT);
            s_prefix = 0;
        } else {
            __hip_atomic_store(&state[b], (1u << 30) | agg, __ATOMIC_RELEASE,
                               __HIP_MEMORY_SCOPE_AGENT);
            unsigned int prefix = 0;
            int p = b - 1;
            while (true) {
                unsigned int s = __hip_atomic_load(&state[p], __ATOMIC_ACQUIRE,
                                                   __HIP_MEMORY_SCOPE_AGENT);
                unsigned int fl = s >> 30;
                if (fl == 0u) { __builtin_amdgcn_s_sleep(1); continue; }
                prefix += s & 0x3FFFFFFFu;
                if (fl == 2u) break;
                --p;
            }
            __hip_atomic_store(&state[b], (2u << 30) | (prefix + agg),
                               __ATOMIC_RELEASE, __HIP_MEMORY_SCOPE_AGENT);
            s_prefix = (int)prefix;
        }
    }
    __syncthreads();

    int off0 = s_prefix + (sd[t] - tt);                 // exclusive offset
    int run = 0;
#pragma unroll
    for (int i = 0; i < 4; ++i) {
        if (base + i < NN) row_ptr[base + i] = off0 + run;
        run += c[i];
    }
    if (b == NBLK - 1 && t == 0) row_ptr[NN] = NE;
}

// ---------------------------------------------------------------- CSR fill
// col[row_ptr[dst] + rank] = src. 8 edges/thread, no atomics in the chain.
__global__ __launch_bounds__(256) void k_fill(const int4* __restrict__ src4,
                                              const int4* __restrict__ dst4,
                                              const int4* __restrict__ rank4,
                                              const int* __restrict__ row_ptr,
                                              int* __restrict__ col) {
    int t = blockIdx.x * 256 + threadIdx.x;   // over NE/8
    if (t >= NE / 8) return;
    int4 s0 = src4[2 * t],  s1 = src4[2 * t + 1];
    int4 d0 = dst4[2 * t],  d1 = dst4[2 * t + 1];
    int4 r0 = rank4[2 * t], r1 = rank4[2 * t + 1];
    int p0 = row_ptr[d0.x], p1 = row_ptr[d0.y], p2 = row_ptr[d0.z], p3 = row_ptr[d0.w];
    int p4 = row_ptr[d1.x], p5 = row_ptr[d1.y], p6 = row_ptr[d1.z], p7 = row_ptr[d1.w];
    col[p0 + r0.x] = s0.x;
    col[p1 + r0.y] = s0.y;
    col[p2 + r0.z] = s0.z;
    col[p3 + r0.w] = s0.w;
    col[p4 + r1.x] = s1.x;
    col[p5 + r1.y] = s1.y;
    col[p6 + r1.z] = s1.z;
    col[p7 + r1.w] = s1.w;
}

// ---------------------------------------------------------------- aggregation (octet-gather)
// Wave = 8 octets x 8 lanes, 2 nodes/wave; lane holds 8 half-features (16 B).
// PROLOGUE-15: each octet takes TWO slots (e+o-1 and e+o+7) -> self + 15 edges
// covered branch-free with 4 independent 1-KB gathers in flight. In-degree ~
// Poisson(8): P(deg<=15) ~ 99%, so the main loop almost never runs; pad slots
// hit the L1-resident zero row NN.
// UMODE==1 (xs UNSCALED): gather applies dinv[r] via FMA (shared with the
//   u-sum broadcast load); writes u1 and p1u = dinv*u1.
// UMODE==2: input prescaled; u-sum over pin=p1u; writes u2.
// UMODE==0: plain aggregate (input prescaled).
// u over-counts 8x (one add per octet lane); fixed by *0.125.
template <int UMODE>
__global__ __launch_bounds__(256) void k_aggregate(
    const __half* __restrict__ x, __half* __restrict__ y,
    const float* __restrict__ scale,
    const int* __restrict__ row_ptr, const int* __restrict__ col,
    const float* __restrict__ dinv, const float* __restrict__ pin,
    float* __restrict__ uout, float* __restrict__ pout) {
    int lane = threadIdx.x & 63;
    int wave = blockIdx.x * 4 + (threadIdx.x >> 6);
    int na = wave * 2;
    if (na >= NN) return;
    int nb = na + 1;                     // NN even: always valid
    int o  = lane >> 3;                  // octet 0..7 (row slot within a step)
    int f8 = (lane & 7) << 3;            // 8-feature base for this lane

    float a[8], b[8];
#pragma unroll
    for (int j = 0; j < 8; ++j) { a[j] = 0.f; b[j] = 0.f; }
    float ua = 0.f, ub = 0.f;

#define GATHER(r, acc, uacc)                                               \
    {                                                                      \
        int4 raw = *(const int4*)(x + (size_t)(r) * HH + f8);              \
        float dr = 1.f;                                                    \
        if (UMODE) { dr = pin[r]; uacc += dr; }                            \
        __half2* hp = (__half2*)&raw;                                      \
        _Pragma("unroll")                                                  \
        for (int j = 0; j < 4; ++j) {                                      \
            float2 f = __half22float2(hp[j]);                              \
            if (UMODE == 1) { acc[2 * j] += dr * f.x; acc[2 * j + 1] += dr * f.y; } \
            else            { acc[2 * j] += f.x;      acc[2 * j + 1] += f.y; }      \
        }                                                                  \
    }

    int ea = row_ptr[na], enda = row_ptr[na + 1];
    int eb = enda,        endb = row_ptr[nb + 1];   // rows adjacent

    // prologue-15: slot0 = self (o==0) / edges 0..6; slot1 = edges 7..14.
    {
        int ia0 = ea + o - 1, ia1 = ea + o + 7;
        int ib0 = eb + o - 1, ib1 = eb + o + 7;
        int rA0 = (o == 0) ? na : ((ia0 < enda) ? col[ia0] : NN);
        int rA1 = (ia1 < enda) ? col[ia1] : NN;
        int rB0 = (o == 0) ? nb : ((ib0 < endb) ? col[ib0] : NN);
        int rB1 = (ib1 < endb) ? col[ib1] : NN;
        GATHER(rA0, a, ua);
        GATHER(rA1, a, ua);
        GATHER(rB0, b, ub);
        GATHER(rB1, b, ub);
        ea += 15; eb += 15;
    }
    // main loop (rare: deg > 15), unrolled x2: 16 edges per node per iteration
    while (ea < enda || eb < endb) {
        int iA0 = ea + o,     iA1 = ea + 8 + o;
        int iB0 = eb + o,     iB1 = eb + 8 + o;
        int rA0 = (iA0 < enda) ? col[iA0] : NN;
        int rA1 = (iA1 < enda) ? col[iA1] : NN;
        int rB0 = (iB0 < endb) ? col[iB0] : NN;
        int rB1 = (iB1 < endb) ? col[iB1] : NN;
        GATHER(rA0, a, ua);
        GATHER(rA1, a, ua);
        GATHER(rB0, b, ub);
        GATHER(rB1, b, ub);
        ea += 16; eb += 16;
    }
#undef GATHER

    // cross-octet reduction: octets differ in lane bits 3,4,5
#pragma unroll
    for (int j = 0; j < 8; ++j) {
        a[j] += __shfl_xor(a[j], 8);  b[j] += __shfl_xor(b[j], 8);
        a[j] += __shfl_xor(a[j], 16); b[j] += __shfl_xor(b[j], 16);
        a[j] += __shfl_xor(a[j], 32); b[j] += __shfl_xor(b[j], 32);
    }
    if (UMODE) {
        ua += __shfl_xor(ua, 8);  ub += __shfl_xor(ub, 8);
        ua += __shfl_xor(ua, 16); ub += __shfl_xor(ub, 16);
        ua += __shfl_xor(ua, 32); ub += __shfl_xor(ub, 32);
    }

    // octets 0/1 store node a / node b rows (8 lanes x 16 B = one 128-B row)
    if (o < 2) {
        int   n  = (o == 0) ? na : nb;
        float dv = scale[n];
        __half2 h[4];
#pragma unroll
        for (int j = 0; j < 4; ++j) {
            float x0 = (o == 0) ? a[2 * j]     : b[2 * j];
            float x1 = (o == 0) ? a[2 * j + 1] : b[2 * j + 1];
            h[j] = __halves2half2(__float2half_rn(dv * x0), __float2half_rn(dv * x1));
        }
        *(int4*)(y + (size_t)n * HH + f8) = *(int4*)h;
    }
    if (UMODE && lane < 2) {
        int n = na + lane;
        float s = ((lane == 0) ? ua : ub) * 0.125f;   // each octet counted 8x
        float dvn = dinv[n];
        float u = dvn * s;
        uout[n] = u;
        if (UMODE == 1) pout[n] = dvn * u;            // prescaled for next u-pass
    }
}

// ---------------------------------------------------------------- final GEMM
// out = (A^3 x0) @ What + u2 c0^T + u1 c1^T + 1 b2^T, split fp32 write.
#define GR 128
#define XSS 65   // +1 pad: conflict-free scalar broadcasts
__global__ __launch_bounds__(256) void k_gemm_final(
    const __half* __restrict__ y, const float* __restrict__ W,
    const float* __restrict__ b2, const float* __restrict__ cvec,
    const float* __restrict__ u1, const float* __restrict__ u2,
    float* __restrict__ out_lo, float* __restrict__ out_hi) {
    __shared__ float xs[GR * XSS];   // 33.3 KB
    __shared__ float ws[HH * HH];    // 16 KB
    int t = threadIdx.x;
    int rowBase = blockIdx.x * GR;

    {   // stage W: 1024 float4 / 256 threads
        const float4* W4 = (const float4*)W;
        float4* ws4 = (float4*)ws;
#pragma unroll
        for (int i = 0; i < 4; ++i) ws4[i * 256 + t] = W4[i * 256 + t];
    }
#pragma unroll
    for (int it = 0; it < 4; ++it) {
        int g = it * 256 + t;        // 0..1023
        int r = g >> 3;
        int c0 = (g & 7) * 8;
        int row = rowBase + r;
        if (row < NN) {
            int4 raw = *(const int4*)(y + (size_t)row * HH + c0);   // 8 halves
            __half2 h0 = *(__half2*)&raw.x, h1 = *(__half2*)&raw.y;
            __half2 h2 = *(__half2*)&raw.z, h3 = *(__half2*)&raw.w;
            float2 f0 = __half22float2(h0), f1 = __half22float2(h1);
            float2 f2 = __half22float2(h2), f3 = __half22float2(h3);
            float* dp = xs + r * XSS + c0;
            dp[0] = f0.x; dp[1] = f0.y; dp[2] = f1.x; dp[3] = f1.y;
            dp[4] = f2.x; dp[5] = f2.y; dp[6] = f3.x; dp[7] = f3.y;
        }
    }
    __syncthreads();

    int tx = t & 7;        // 8 col-groups of 8
    int ty = t >> 3;       // 32 row-groups of 4
    int j0 = tx * 8;
    int r0 = ty * 4;

    float acc[4][8];
#pragma unroll
    for (int i = 0; i < 4; ++i)
#pragma unroll
        for (int j = 0; j < 8; ++j) acc[i][j] = 0.f;

    for (int k = 0; k < HH; ++k) {
        float4 w0 = *(const float4*)(ws + k * HH + j0);
        float4 w1 = *(const float4*)(ws + k * HH + j0 + 4);
        float wv[8] = {w0.x, w0.y, w0.z, w0.w, w1.x, w1.y, w1.z, w1.w};
#pragma unroll
        for (int i = 0; i < 4; ++i) {
            float xv = xs[(r0 + i) * XSS + k];
#pragma unroll
            for (int j = 0; j < 8; ++j) acc[i][j] += xv * wv[j];
        }
    }

    float c0j[8], c1j[8], b2j[8];
#pragma unroll
    for (int j = 0; j < 8; ++j) {
        c0j[j] = cvec[j0 + j];
        c1j[j] = cvec[HH + j0 + j];
        b2j[j] = b2[j0 + j];
    }

#pragma unroll
    for (int i = 0; i < 4; ++i) {
        int r = rowBase + r0 + i;
        if (r >= NN) continue;
        float u2r = u2[r], u1r = u1[r];
        float base[8];
#pragma unroll
        for (int j = 0; j < 8; ++j) base[j] = u2r * c0j[j] + u1r * c1j[j] + b2j[j];
        float4 o0 = make_float4(acc[i][0] + base[0], acc[i][1] + base[1],
                                acc[i][2] + base[2], acc[i][3] + base[3]);
        float4 o1 = make_float4(acc[i][4] + base[4], acc[i][5] + base[5],
                                acc[i][6] + base[6], acc[i][7] + base[7]);
        float* d = (r < NU) ? (out_lo + (size_t)r * HH)
                            : (out_hi + (size_t)(r - NU) * HH);
        *(float4*)(d + j0) = o0;
        *(float4*)(d + j0 + 4) = o1;
    }
}

// ---------------------------------------------------------------- launch
extern "C" void kernel_launch(void* const* d_in, const int* in_sizes, int n_in,
                              void* d_out, int out_size, void* d_ws, size_t ws_size,
                              hipStream_t stream) {
    const int*   edge  = (const int*)d_in[0];
    const int*   src   = edge;           // edge_index[0]
    const int*   dst   = edge + NE;      // edge_index[1]
    const float* users = (const float*)d_in[1];
    const float* items = (const float*)d_in[2];
    const float* Ws    = (const float*)d_in[3];   // [3][64][64]
    const float* bs    = (const float*)d_in[4];   // [3][64]
    float*       out   = (float*)d_out;

    // workspace carve (~52 MB). Xs row NN, dinv[NN], p1u[NN] are zeroed pads
    // (rank block 0). state sits directly before counts: one memset covers both.
    char* w = (char*)d_ws;
    __half* Xs0     = (__half*)w; w += (size_t)(NN + 1) * HH * 2;   // 19.2 MB
    __half* Xs1     = (__half*)w; w += (size_t)(NN + 1) * HH * 2;   // 19.2 MB
    float*  dinv    = (float*)w;  w += (size_t)(NN + 1) * 4;
    float*  dinv2   = (float*)w;  w += (size_t)NN * 4;
    float*  u1      = (float*)w;  w += (size_t)NN * 4;
    float*  p1u     = (float*)w;  w += (size_t)(NN + 1) * 4;
    float*  u2      = (float*)w;  w += (size_t)NN * 4;
    float*  What    = (float*)w;  w += (size_t)HH * HH * 4;         // 16 KB
    float*  cvec    = (float*)w;  w += (size_t)2 * HH * 4;          // c0, c1
    unsigned int* state = (unsigned int*)w; w += 256 * 4;
    int*    counts  = (int*)w;    w += (size_t)NN * 4;
    int*    row_ptr = (int*)w;    w += (size_t)(NN + 1) * 4;
    w += 12;                                                  // realign to 16
    int*    col     = (int*)w;    w += (size_t)NE * 4;        // 4.8 MB
    int*    rank    = (int*)w;    w += (size_t)NE * 4;        // 4.8 MB
    (void)ws_size; (void)in_sizes; (void)n_in; (void)out_size;

    hipMemsetAsync(state, 0, (size_t)(256 + NN) * sizeof(int), stream);

    k_rank_concat<<<RANK_BLOCKS + CONCAT4_BLOCKS, 256, 0, stream>>>(
        (const int4*)dst, counts, (int4*)rank,
        (const float4*)users, (const float4*)items, (__half2*)Xs0, (float4*)out,
        Xs0 + (size_t)NN * HH, Xs1 + (size_t)NN * HH, dinv, p1u);
    k_scan<<<NBLK + 1, 256, 0, stream>>>(counts, dinv, dinv2, row_ptr, state,
                                         Ws, bs, What, cvec);
    k_fill<<<FILL_BLOCKS, 256, 0, stream>>>(
        (const int4*)src, (const int4*)dst, (const int4*)rank, row_ptr, col);

    // A^3 chain (u-sums + layer-1 dinv prescale folded into the gather loops)
    k_aggregate<1><<<AGG_BLOCKS, 256, 0, stream>>>(
        Xs0, Xs1, dinv2, row_ptr, col, dinv, dinv, u1, p1u);
    k_aggregate<2><<<AGG_BLOCKS, 256, 0, stream>>>(
        Xs1, Xs0, dinv2, row_ptr, col, dinv, p1u, u2, nullptr);
    k_aggregate<0><<<AGG_BLOCKS, 256, 0, stream>>>(
        Xs0, Xs1, dinv, row_ptr, col, nullptr, nullptr, nullptr, nullptr);

    const int GEMM_BLOCKS = (NN + GR - 1) / GR;
    k_gemm_final<<<GEMM_BLOCKS, 256, 0, stream>>>(
        Xs1, What, bs + 2 * HH, cvec, u1, u2,
        out /* x_users */, out + (size_t)2 * NU * HH /* x_items */);
}